// Round 12
// baseline (45.078 us; speedup 1.0000x reference)
//
#include <hip/hip_runtime.h>

// N_TOTAL=10100, D=128, B=2048. F dense-stored, ~33 nnz/row.
// 4 rows per block (grid 512, TPB 256), software-pipelined:
//   issue row r+1's 10 float4 loads into the spare register buffer BEFORE
//   processing row r (compaction -> P2 gather -> P3 linear). Tails (latency-
//   bound P2/P3 + barriers) hide under the next row's stream; 2 blocks/CU
//   overlap each other as well. Per-row machinery identical to R6/R11.

#define NTOT 10100
#define NV4  2525     // NTOT/4 exact
#define DIM  128
#define CAP  256      // nnz ~ Poisson(32); dense fallback if exceeded
#define TPB  256
#define NLD  10       // ceil(NV4/TPB)
#define RPB  4        // rows per block

__global__ __launch_bounds__(TPB) void friendship_kernel(
    const int*   __restrict__ uids,
    const float* __restrict__ F,
    const float* __restrict__ E,
    const float* __restrict__ W,
    const float* __restrict__ bias,
    float*       __restrict__ out,
    int B)
{
    __shared__ int   s_idx[CAP];
    __shared__ float s_w[CAP];
    __shared__ int   s_cnt;
    __shared__ float s_red[8][DIM];
    __shared__ float s_agg[DIM];
    __shared__ float s_out[DIM];

    const int tid  = threadIdx.x;
    const int base = blockIdx.x * RPB;
    const int g = tid >> 5;    // entry-group 0..7
    const int l = tid & 31;    // lane owns d = 4l..4l+3

    int uid[RPB];
    #pragma unroll
    for (int r = 0; r < RPB; ++r)
        uid[r] = (base + r < B) ? uids[base + r] : uids[0];

    if (tid == 0) s_cnt = 0;

    float4 bufA[NLD], bufB[NLD];
    {   // prefetch row 0 -> A
        const float4* Fr4 = (const float4*)(F + (size_t)uid[0] * NTOT);
        #pragma unroll
        for (int t = 0; t < NLD; ++t) {
            int i = tid + t * TPB; int ic = (i < NV4) ? i : (NV4 - 1);
            bufA[t] = Fr4[ic];
        }
    }

    #pragma unroll
    for (int r = 0; r < RPB; ++r) {
        // ---- issue next row's loads into the spare buffer (no wait) ----
        if (r + 1 < RPB) {
            const float4* Fr4 = (const float4*)(F + (size_t)uid[r + 1] * NTOT);
            if (r & 1) {
                #pragma unroll
                for (int t = 0; t < NLD; ++t) {
                    int i = tid + t * TPB; int ic = (i < NV4) ? i : (NV4 - 1);
                    bufA[t] = Fr4[ic];
                }
            } else {
                #pragma unroll
                for (int t = 0; t < NLD; ++t) {
                    int i = tid + t * TPB; int ic = (i < NV4) ? i : (NV4 - 1);
                    bufB[t] = Fr4[ic];
                }
            }
        }
        __syncthreads();   // s_cnt reset visible; prev row's LDS consumers done

        // ---- compaction of current row's registers (one atomic per hit chunk) ----
        #pragma unroll
        for (int t = 0; t < NLD; ++t) {
            float4 vv = (r & 1) ? bufB[t] : bufA[t];   // r is compile-time (unrolled)
            int i = tid + t * TPB;
            if (i < NV4) {
                int n = i * 4;
                bool ba = vv.x != 0.0f, bb = vv.y != 0.0f, bc = vv.z != 0.0f, bd = vv.w != 0.0f;
                int  m  = (int)ba + (int)bb + (int)bc + (int)bd;
                if (m) {
                    int p = atomicAdd(&s_cnt, m);
                    if (p + m <= CAP) {
                        if (ba) { s_idx[p] = n;     s_w[p] = vv.x; ++p; }
                        if (bb) { s_idx[p] = n + 1; s_w[p] = vv.y; ++p; }
                        if (bc) { s_idx[p] = n + 2; s_w[p] = vv.z; ++p; }
                        if (bd) { s_idx[p] = n + 3; s_w[p] = vv.w; ++p; }
                    }
                }
            }
        }
        __syncthreads();
        const int cnt = s_cnt;

        // ---- P2: agg[d] = sum_k w_k * E[n_k][d]; 8 groups x 32 lanes ----
        float4 acc = make_float4(0.f, 0.f, 0.f, 0.f);
        if (cnt <= CAP) {
            int k = g;
            for (; k + 8 < cnt; k += 16) {
                int   n0 = s_idx[k];     float w0 = s_w[k];
                int   n1 = s_idx[k + 8]; float w1 = s_w[k + 8];
                float4 e0 = *(const float4*)(E + (size_t)n0 * DIM + l * 4);
                float4 e1 = *(const float4*)(E + (size_t)n1 * DIM + l * 4);
                acc.x += w0 * e0.x; acc.y += w0 * e0.y; acc.z += w0 * e0.z; acc.w += w0 * e0.w;
                acc.x += w1 * e1.x; acc.y += w1 * e1.y; acc.z += w1 * e1.z; acc.w += w1 * e1.w;
            }
            for (; k < cnt; k += 8) {
                int   n = s_idx[k];
                float w = s_w[k];
                float4 ev = *(const float4*)(E + (size_t)n * DIM + l * 4);
                acc.x += w * ev.x; acc.y += w * ev.y; acc.z += w * ev.z; acc.w += w * ev.w;
            }
        } else {
            const float* Frow = F + (size_t)uid[r] * NTOT;   // never taken; correctness net
            for (int n = g; n < NTOT; n += 8) {
                float w = Frow[n];
                float4 ev = *(const float4*)(E + (size_t)n * DIM + l * 4);
                acc.x += w * ev.x; acc.y += w * ev.y; acc.z += w * ev.z; acc.w += w * ev.w;
            }
        }
        *(float4*)&s_red[g][l * 4] = acc;
        __syncthreads();

        if (tid < DIM) {
            float sum = 0.0f;
            #pragma unroll
            for (int gg = 0; gg < 8; ++gg) sum += s_red[gg][tid];
            s_agg[tid] = sum;
        }
        __syncthreads();

        // ---- P3: out[j] = bias[j] + sum_d agg[d]*W[j][d]; coalesced W ----
        const float4* W4 = (const float4*)W;
        #pragma unroll
        for (int q = 0; q < 16; ++q) {
            int i4 = tid + TPB * q;          // flat float4 index 0..4095
            float4 wv = W4[i4];              // fully coalesced, L1/L2-hot after row 0
            int j  = i4 >> 5;
            int dd = (i4 & 31) * 4;
            float4 ag = *(const float4*)&s_agg[dd];
            float p = wv.x * ag.x + wv.y * ag.y + wv.z * ag.z + wv.w * ag.w;
            p += __shfl_xor(p, 16);
            p += __shfl_xor(p, 8);
            p += __shfl_xor(p, 4);
            p += __shfl_xor(p, 2);
            p += __shfl_xor(p, 1);
            if ((tid & 31) == 0) s_out[j] = p;
        }
        __syncthreads();
        if (tid < DIM && base + r < B)
            out[(size_t)(base + r) * DIM + tid] = bias[tid] + s_out[tid];
        if (tid == 0) s_cnt = 0;   // reset for next row (visible after top barrier)
    }
}

extern "C" void kernel_launch(void* const* d_in, const int* in_sizes, int n_in,
                              void* d_out, int out_size, void* d_ws, size_t ws_size,
                              hipStream_t stream) {
    const int*   uids = (const int*)  d_in[0];
    const float* F    = (const float*)d_in[1];
    const float* E    = (const float*)d_in[2];
    const float* W    = (const float*)d_in[3];
    const float* bias = (const float*)d_in[4];
    float*       out  = (float*)d_out;

    const int B = in_sizes[0];  // 2048
    friendship_kernel<<<(B + RPB - 1) / RPB, TPB, 0, stream>>>(uids, F, E, W, bias, out, B);
}

// Round 13
// 43.165 us; speedup vs baseline: 1.0443x; 1.0443x over previous
//
#include <hip/hip_runtime.h>

// N_TOTAL=10100, D=128, B=2048. F dense-stored, ~33 nnz/row.
// One row per block, TPB=256 (4 waves). NEW: the F-row is streamed into LDS
// via global_load_lds DMA (10 x 1KB rounds per wave, fire-and-forget), and
// rounds are processed with COUNTED vmcnt waits so round t is compacted while
// rounds t+1.. are still in flight. Compaction is wave-private (own list +
// own LDS counter -> no cross-wave races, no barrier until the reduce).
// P2: per-wave sparse aggregate, lane owns d=(2l,2l+1). P3: R6's coalesced-W
// epilogue.

#define NTOT 10100
#define NV4  2525     // NTOT/4 exact
#define DIM  128
#define TPB  256
#define NRND 10       // DMA rounds per wave (64 chunks = 1KB each)
#define WCAP 96       // per-wave (quarter-row) capacity; nnz/quarter ~ Poisson(8.25)

__device__ __forceinline__ void wait_vmcnt(int n) {
    switch (n) {
        case 0: asm volatile("s_waitcnt vmcnt(0)" ::: "memory"); break;
        case 1: asm volatile("s_waitcnt vmcnt(1)" ::: "memory"); break;
        case 2: asm volatile("s_waitcnt vmcnt(2)" ::: "memory"); break;
        case 3: asm volatile("s_waitcnt vmcnt(3)" ::: "memory"); break;
        case 4: asm volatile("s_waitcnt vmcnt(4)" ::: "memory"); break;
        case 5: asm volatile("s_waitcnt vmcnt(5)" ::: "memory"); break;
        case 6: asm volatile("s_waitcnt vmcnt(6)" ::: "memory"); break;
        case 7: asm volatile("s_waitcnt vmcnt(7)" ::: "memory"); break;
        case 8: asm volatile("s_waitcnt vmcnt(8)" ::: "memory"); break;
        default: asm volatile("s_waitcnt vmcnt(9)" ::: "memory"); break;
    }
}

__global__ __launch_bounds__(TPB) void friendship_kernel(
    const int*   __restrict__ uids,
    const float* __restrict__ F,
    const float* __restrict__ E,
    const float* __restrict__ W,
    const float* __restrict__ bias,
    float*       __restrict__ out)
{
    __shared__ __align__(16) float4 s_row[4 * NRND * 64];   // 40960 B row stage
    __shared__ int   s_idx[4][WCAP];
    __shared__ float s_w[4][WCAP];
    __shared__ int   s_cnt[4];
    __shared__ float s_part[4][DIM];
    __shared__ float s_agg[DIM];
    __shared__ float s_out[DIM];

    const int row  = blockIdx.x;
    const int tid  = threadIdx.x;
    const int w    = tid >> 6;          // wave 0..3 owns chunks [640w, 640w+640)
    const int lane = tid & 63;
    const int uid  = uids[row];
    const float* Frow = F + (size_t)uid * NTOT;
    const float4* Frow4 = (const float4*)Frow;   // uid*40400 % 16 == 0

    if (lane == 0) s_cnt[w] = 0;   // wave-private; program order within wave

    // normalize vmcnt so exactly our 10 DMAs are counted
    asm volatile("s_waitcnt vmcnt(0)" ::: "memory");

    // ---- issue all 10 DMA rounds (1KB per wave each), fire-and-forget ----
    #pragma unroll
    for (int t = 0; t < NRND; ++t) {
        int j  = 640 * w + 64 * t + lane;
        int jc = (j < NV4) ? j : (NV4 - 1);     // clamp keeps address valid
        __builtin_amdgcn_global_load_lds(
            (const __attribute__((address_space(1))) void*)(Frow4 + jc),
            (__attribute__((address_space(3))) void*)&s_row[(w * NRND + t) * 64],
            16, 0, 0);
    }

    // ---- process round t while rounds t+1.. are still in flight ----
    #pragma unroll
    for (int t = 0; t < NRND; ++t) {
        wait_vmcnt(NRND - 1 - t);
        __builtin_amdgcn_sched_barrier(0);
        float4 vv = s_row[(w * NRND + t) * 64 + lane];
        int i = 640 * w + 64 * t + lane;
        if (i < NV4) {
            int n = i * 4;
            bool ba = vv.x != 0.0f, bb = vv.y != 0.0f, bc = vv.z != 0.0f, bd = vv.w != 0.0f;
            int  m  = (int)ba + (int)bb + (int)bc + (int)bd;
            if (m) {
                int p = atomicAdd(&s_cnt[w], m);
                if (p + m <= WCAP) {
                    if (ba) { s_idx[w][p] = n;     s_w[w][p] = vv.x; ++p; }
                    if (bb) { s_idx[w][p] = n + 1; s_w[w][p] = vv.y; ++p; }
                    if (bc) { s_idx[w][p] = n + 2; s_w[w][p] = vv.z; ++p; }
                    if (bd) { s_idx[w][p] = n + 3; s_w[w][p] = vv.w; ++p; }
                }
            }
        }
    }
    // own wave's ds ops complete & visible (wave lockstep)
    asm volatile("s_waitcnt lgkmcnt(0)" ::: "memory");
    __builtin_amdgcn_sched_barrier(0);

    const int cnt = s_cnt[w];

    // ---- P2: wave-level aggregate; lane owns d = (2*lane, 2*lane+1) ----
    float2 acc = make_float2(0.0f, 0.0f);
    const float* Ed = E + 2 * lane;
    if (cnt <= WCAP) {
        int k = 0;
        for (; k + 4 <= cnt; k += 4) {
            int   n0 = s_idx[w][k],     n1 = s_idx[w][k + 1];
            int   n2 = s_idx[w][k + 2], n3 = s_idx[w][k + 3];
            float w0 = s_w[w][k],       w1 = s_w[w][k + 1];
            float w2 = s_w[w][k + 2],   w3 = s_w[w][k + 3];
            float2 e0 = *(const float2*)(Ed + (size_t)n0 * DIM);
            float2 e1 = *(const float2*)(Ed + (size_t)n1 * DIM);
            float2 e2 = *(const float2*)(Ed + (size_t)n2 * DIM);
            float2 e3 = *(const float2*)(Ed + (size_t)n3 * DIM);
            acc.x += w0 * e0.x; acc.y += w0 * e0.y;
            acc.x += w1 * e1.x; acc.y += w1 * e1.y;
            acc.x += w2 * e2.x; acc.y += w2 * e2.y;
            acc.x += w3 * e3.x; acc.y += w3 * e3.y;
        }
        for (; k < cnt; ++k) {
            int   n  = s_idx[w][k];
            float ww = s_w[w][k];
            float2 ev = *(const float2*)(Ed + (size_t)n * DIM);
            acc.x += ww * ev.x; acc.y += ww * ev.y;
        }
    } else {
        // dense fallback over this wave's element range (never taken)
        const int nbeg = 2560 * w;
        const int nend = (w == 3) ? NTOT : 2560 * (w + 1);
        for (int n = nbeg; n < nend; ++n) {
            float fw = Frow[n];
            if (fw != 0.0f) {
                float2 ev = *(const float2*)(Ed + (size_t)n * DIM);
                acc.x += fw * ev.x; acc.y += fw * ev.y;
            }
        }
    }
    *(float2*)&s_part[w][2 * lane] = acc;
    __syncthreads();

    // ---- cross-wave reduce ----
    if (tid < DIM)
        s_agg[tid] = s_part[0][tid] + s_part[1][tid] + s_part[2][tid] + s_part[3][tid];
    __syncthreads();

    // ---- P3: out[j] = bias[j] + sum_d agg[d]*W[j][d]; coalesced W ----
    const float4* W4 = (const float4*)W;
    #pragma unroll
    for (int q = 0; q < 16; ++q) {
        int i4 = tid + TPB * q;          // flat float4 index 0..4095
        float4 wv = W4[i4];              // fully coalesced, L2-hot
        int j  = i4 >> 5;
        int dd = (i4 & 31) * 4;
        float4 ag = *(const float4*)&s_agg[dd];
        float p = wv.x * ag.x + wv.y * ag.y + wv.z * ag.z + wv.w * ag.w;
        p += __shfl_xor(p, 16);
        p += __shfl_xor(p, 8);
        p += __shfl_xor(p, 4);
        p += __shfl_xor(p, 2);
        p += __shfl_xor(p, 1);
        if ((tid & 31) == 0) s_out[j] = p;
    }
    __syncthreads();
    if (tid < DIM)
        out[(size_t)row * DIM + tid] = bias[tid] + s_out[tid];
}

extern "C" void kernel_launch(void* const* d_in, const int* in_sizes, int n_in,
                              void* d_out, int out_size, void* d_ws, size_t ws_size,
                              hipStream_t stream) {
    const int*   uids = (const int*)  d_in[0];
    const float* F    = (const float*)d_in[1];
    const float* E    = (const float*)d_in[2];
    const float* W    = (const float*)d_in[3];
    const float* bias = (const float*)d_in[4];
    float*       out  = (float*)d_out;

    const int B = in_sizes[0];  // 2048
    friendship_kernel<<<B, TPB, 0, stream>>>(uids, F, E, W, bias, out);
}